// Round 18
// baseline (106321.313 us; speedup 1.0000x reference)
//
#include <hip/hip_runtime.h>

// ---- problem constants ----
constexpr int SQ = 8192;   // sequence length
constexpr int HD = 256;    // hidden size H
constexpr int NG = 1024;   // 4H (gate width)

typedef __fp16 h2 __attribute__((ext_vector_type(2)));
typedef __fp16 f16x8 __attribute__((ext_vector_type(8)));
typedef float f32x4 __attribute__((ext_vector_type(4)));
typedef unsigned int uint;
typedef unsigned short ushort;

__device__ __forceinline__ float sigm_f(float x) {
  float e = __builtin_amdgcn_exp2f(-1.4426950408889634f * x);
  return __builtin_amdgcn_rcpf(1.0f + e);
}
__device__ __forceinline__ float tanh_f(float x) {
  float e = __builtin_amdgcn_exp2f(2.885390081777927f * x);
  return 1.0f - 2.0f * __builtin_amdgcn_rcpf(1.0f + e);
}
__device__ __forceinline__ h2 bch2(uint v) { return __builtin_bit_cast(h2, v); }
__device__ __forceinline__ uint pk(float a, float b) {
  return __builtin_bit_cast(uint, __builtin_amdgcn_cvt_pkrtz(a, b));
}
__device__ __forceinline__ f16x8 bcf(uint4 v) { return __builtin_bit_cast(f16x8, v); }
// xor lane-bit-0 exchange via DPP quad_perm [1,0,3,2] — pure VALU
__device__ __forceinline__ float dpp_xor1(float x) {
  int v = __builtin_amdgcn_mov_dpp(__builtin_bit_cast(int, x), 0xB1, 0xF, 0xF, true);
  return __builtin_bit_cast(float, v);
}

// =====================================================================
// xp GEMM via MFMA, split-f16 3-term — byte-exact from round 16/17
// (verified: absmax 0, ~2.85 ms total residual with cls).
// =====================================================================
__global__ __launch_bounds__(256) void gemm_mfma(const float* __restrict__ A, int K,
                                                 const float* __restrict__ W,
                                                 const float* __restrict__ bias,
                                                 float* __restrict__ out) {
  __shared__ __fp16 Ahi[64][40];
  __shared__ __fp16 Alo[64][40];
  __shared__ __fp16 Bhi[64][40];   // transposed: [n][k]
  __shared__ __fp16 Blo[64][40];
  const int tid = threadIdx.x;
  const int w   = tid >> 6;
  const int l   = tid & 63;
  const int bm  = blockIdx.x * 64;
  const int d   = blockIdx.y >> 4;
  const int bn  = (blockIdx.y & 15) * 64;
  const float* Wd = W + (size_t)d * K * NG;
  const float* bd = bias + (size_t)d * NG;
  float* outd = out + (size_t)d * SQ * NG;

  const int ar = tid >> 2, ac8 = (tid & 3) * 8;
  const int br = tid >> 3, bc8 = (tid & 7) * 8;

  f32x4 c[4] = {{0.f, 0.f, 0.f, 0.f}, {0.f, 0.f, 0.f, 0.f},
                {0.f, 0.f, 0.f, 0.f}, {0.f, 0.f, 0.f, 0.f}};

  for (int kt = 0; kt < K; kt += 32) {
    float4 a0 = *(const float4*)(A + (size_t)(bm + ar) * K + kt + ac8);
    float4 a1 = *(const float4*)(A + (size_t)(bm + ar) * K + kt + ac8 + 4);
    float4 b0 = *(const float4*)(Wd + (size_t)(kt + br) * NG + bn + bc8);
    float4 b1 = *(const float4*)(Wd + (size_t)(kt + br) * NG + bn + bc8 + 4);
    __syncthreads();
    {
      float av[8] = {a0.x, a0.y, a0.z, a0.w, a1.x, a1.y, a1.z, a1.w};
      __fp16 hi[8], lo[8];
#pragma unroll
      for (int i = 0; i < 8; ++i) {
        hi[i] = (__fp16)av[i];
        lo[i] = (__fp16)(av[i] - (float)hi[i]);
      }
      *(uint4*)&Ahi[ar][ac8] = *(const uint4*)hi;
      *(uint4*)&Alo[ar][ac8] = *(const uint4*)lo;
    }
    {
      float bv[8] = {b0.x, b0.y, b0.z, b0.w, b1.x, b1.y, b1.z, b1.w};
#pragma unroll
      for (int i = 0; i < 8; ++i) {
        __fp16 hi = (__fp16)bv[i];
        Bhi[bc8 + i][br] = hi;
        Blo[bc8 + i][br] = (__fp16)(bv[i] - (float)hi);
      }
    }
    __syncthreads();
    f16x8 ah = bcf(*(const uint4*)&Ahi[w * 16 + (l & 15)][(l >> 4) * 8]);
    f16x8 al = bcf(*(const uint4*)&Alo[w * 16 + (l & 15)][(l >> 4) * 8]);
#pragma unroll
    for (int nt = 0; nt < 4; ++nt) {
      f16x8 bh = bcf(*(const uint4*)&Bhi[nt * 16 + (l & 15)][(l >> 4) * 8]);
      f16x8 bl = bcf(*(const uint4*)&Blo[nt * 16 + (l & 15)][(l >> 4) * 8]);
      c[nt] = __builtin_amdgcn_mfma_f32_16x16x32_f16(ah, bh, c[nt], 0, 0, 0);
      c[nt] = __builtin_amdgcn_mfma_f32_16x16x32_f16(al, bh, c[nt], 0, 0, 0);
      c[nt] = __builtin_amdgcn_mfma_f32_16x16x32_f16(ah, bl, c[nt], 0, 0, 0);
    }
  }

#pragma unroll
  for (int nt = 0; nt < 4; ++nt) {
    const int col = bn + nt * 16 + (l & 15);
    const float bb = bd[col];
#pragma unroll
    for (int r = 0; r < 4; ++r) {
      const int row = bm + w * 16 + (l >> 4) * 4 + r;
      outd[(size_t)row * NG + col] = c[nt][r] + bb;
    }
  }
}

#define FRAGQ(b) bcf(make_uint4(wregd[(b)], wregd[(b) + 1], wregd[(b) + 2], wregd[(b) + 3]))

// =====================================================================
// LSTM recurrence v25 (HYBRID): both compute pipes at once.
// 512 threads (8 waves). Waves 0-3 = MFMA path (v13, HW-verified) on
// units 0..127; waves 4-7 = fdot2 path (v12, HW-verified) on units
// 128..255. Both paths' weights are exactly 192 dwords/thread and live
// in ONE overlaid register array wregd[192] (branch-dependent contents)
// so the union costs 192 regs, not 384.
//   MFMA wave m (=w): units [m*32,m*32+32); cg c: colb=(c>>1)*256+
//     m*32+(c&1)*16+col16; cgs 0-5 in wregd (f16x8 frags), cgs 6-7 in
//     wlA[16*256] (64KB). A-frag = h slice broadcast; pre[c]=C[0].
//   fdot2 wave: jv=j-256, uv=128+(jv>>1), s=jv&1; rows [s*128,+96) in
//     wregd (h2), rows +96..128 in wlV[16*256] (64KB); DPP-xor1 combine.
// Disjoint unit coverage; both tails redundant-exact; h f16 writes to
// parity buffer; ONE raw lgkmcnt-only s_barrier/step.
// LDS 129KB -> 1 block/CU.
// =====================================================================
__global__ __launch_bounds__(512, 1) void lstm_hyb(const float* __restrict__ Whh,
                                                   const float* __restrict__ xp,
                                                   float* __restrict__ obuf) {
  __shared__ uint4 wlA[16 * 256];   // 64KB: [(c6*8+ks)][m*64+l]
  __shared__ uint4 wlV[16 * 256];   // 64KB: [(g*4+qq)][jv]
  __shared__ uint  hl[2][128];      // h f16-packed: dword r = (h[2r],h[2r+1])
  const int d = blockIdx.x;
  const int j = threadIdx.x;
  const int w = j >> 6;
  const int l = j & 63;
  const float* W   = Whh + (size_t)d * HD * NG;
  const float* xpd = xp + (size_t)d * SQ * NG;

  // MFMA-path ids
  const int col16 = l & 15;
  const int g4 = l >> 4;
  const int m = w;                       // 0..3 valid in MFMA branch
  const int u0 = m * 32 + col16, u1 = u0 + 16;
  // fdot2-path ids
  const int jv = j & 255;
  const int uv = 128 + (jv >> 1);
  const int s  = jv & 1;

  uint wregd[192];                       // overlaid weight storage
  const int fwd = (d == 0) ? 1 : 0;
  const int t0 = fwd ? 0 : SQ - 1;
  const int dt = fwd ? 1 : -1;
  float xc[8], xn[8] = {};

  if (w < 4) {
    // ---- MFMA weights: cgs 0..5 -> wregd, cgs 6..7 -> wlA ----
#pragma unroll
    for (int c = 0; c < 6; ++c) {
      const int colb = (c >> 1) * 256 + m * 32 + (c & 1) * 16 + col16;
#pragma unroll
      for (int ks = 0; ks < 8; ++ks) {
        const int r0 = ks * 32 + g4 * 8;
        const int b = (c * 8 + ks) * 4;
        wregd[b + 0] = pk(W[(size_t)(r0 + 0) * NG + colb], W[(size_t)(r0 + 1) * NG + colb]);
        wregd[b + 1] = pk(W[(size_t)(r0 + 2) * NG + colb], W[(size_t)(r0 + 3) * NG + colb]);
        wregd[b + 2] = pk(W[(size_t)(r0 + 4) * NG + colb], W[(size_t)(r0 + 5) * NG + colb]);
        wregd[b + 3] = pk(W[(size_t)(r0 + 6) * NG + colb], W[(size_t)(r0 + 7) * NG + colb]);
      }
    }
#pragma unroll
    for (int c6 = 0; c6 < 2; ++c6) {
      const int colb = 768 + m * 32 + c6 * 16 + col16;
#pragma unroll
      for (int ks = 0; ks < 8; ++ks) {
        const int r0 = ks * 32 + g4 * 8;
        uint4 v;
        v.x = pk(W[(size_t)(r0 + 0) * NG + colb], W[(size_t)(r0 + 1) * NG + colb]);
        v.y = pk(W[(size_t)(r0 + 2) * NG + colb], W[(size_t)(r0 + 3) * NG + colb]);
        v.z = pk(W[(size_t)(r0 + 4) * NG + colb], W[(size_t)(r0 + 5) * NG + colb]);
        v.w = pk(W[(size_t)(r0 + 6) * NG + colb], W[(size_t)(r0 + 7) * NG + colb]);
        wlA[(c6 * 8 + ks) * 256 + m * 64 + l] = v;
      }
    }
#pragma unroll
    for (int c = 0; c < 8; ++c)
      xc[c] = xpd[(size_t)t0 * NG + (c >> 1) * 256 + m * 32 + (c & 1) * 16 + col16];
  } else {
    // ---- fdot2 weights: rows [s*128,+96) -> wregd, rows +96..128 -> wlV ----
#pragma unroll
    for (int g = 0; g < 4; ++g) {
      const float* Wc = W + (size_t)(s * 128) * NG + g * 256 + uv;
#pragma unroll
      for (int k = 0; k < 48; ++k)
        wregd[g * 48 + k] = pk(Wc[(size_t)(2 * k) * NG], Wc[(size_t)(2 * k + 1) * NG]);
    }
#pragma unroll
    for (int g = 0; g < 4; ++g) {
#pragma unroll
      for (int qq = 0; qq < 4; ++qq) {
        const int r0 = s * 128 + 96 + 8 * qq;
        const int c = g * 256 + uv;
        uint4 v;
        v.x = pk(W[(size_t)(r0 + 0) * NG + c], W[(size_t)(r0 + 1) * NG + c]);
        v.y = pk(W[(size_t)(r0 + 2) * NG + c], W[(size_t)(r0 + 3) * NG + c]);
        v.z = pk(W[(size_t)(r0 + 4) * NG + c], W[(size_t)(r0 + 5) * NG + c]);
        v.w = pk(W[(size_t)(r0 + 6) * NG + c], W[(size_t)(r0 + 7) * NG + c]);
        wlV[(g * 4 + qq) * 256 + jv] = v;
      }
    }
#pragma unroll
    for (int g = 0; g < 4; ++g) xc[g] = xpd[(size_t)t0 * NG + g * 256 + uv];
  }

  if (j < 256) ((uint*)hl)[j] = 0u;
  __syncthreads();

  int t = t0;
  float cc0 = 0.0f, cc1 = 0.0f;    // MFMA-path state (u0, u1)
  float cc  = 0.0f;                // fdot2-path state (uv)
  int p = 0;

  for (int step = 0; step < SQ; ++step) {
    if (w < 4) {
      // ================= MFMA path (units 0..127) =================
      if (step + 1 < SQ) {
#pragma unroll
        for (int c = 0; c < 8; ++c)
          xn[c] = xpd[(size_t)(t + dt) * NG + (c >> 1) * 256 + m * 32 + (c & 1) * 16 + col16];
      }
      float pre[8];
      {
        f32x4 c0 = {0.f, 0.f, 0.f, 0.f}, c1 = c0, c2 = c0, c3 = c0;
#pragma unroll
        for (int ks = 0; ks < 8; ++ks) {
          f16x8 a = bcf(*(const uint4*)&hl[p][ks * 16 + g4 * 4]);
          c0 = __builtin_amdgcn_mfma_f32_16x16x32_f16(a, FRAGQ((0 * 8 + ks) * 4), c0, 0, 0, 0);
          c1 = __builtin_amdgcn_mfma_f32_16x16x32_f16(a, FRAGQ((1 * 8 + ks) * 4), c1, 0, 0, 0);
          c2 = __builtin_amdgcn_mfma_f32_16x16x32_f16(a, FRAGQ((2 * 8 + ks) * 4), c2, 0, 0, 0);
          c3 = __builtin_amdgcn_mfma_f32_16x16x32_f16(a, FRAGQ((3 * 8 + ks) * 4), c3, 0, 0, 0);
        }
        pre[0] = c0[0]; pre[1] = c1[0]; pre[2] = c2[0]; pre[3] = c3[0];
      }
      {
        f32x4 c0 = {0.f, 0.f, 0.f, 0.f}, c1 = c0, c2 = c0, c3 = c0;
#pragma unroll
        for (int ks = 0; ks < 8; ++ks) {
          f16x8 a = bcf(*(const uint4*)&hl[p][ks * 16 + g4 * 4]);
          c0 = __builtin_amdgcn_mfma_f32_16x16x32_f16(a, FRAGQ((4 * 8 + ks) * 4), c0, 0, 0, 0);
          c1 = __builtin_amdgcn_mfma_f32_16x16x32_f16(a, FRAGQ((5 * 8 + ks) * 4), c1, 0, 0, 0);
          c2 = __builtin_amdgcn_mfma_f32_16x16x32_f16(a, bcf(wlA[(0 * 8 + ks) * 256 + m * 64 + l]), c2, 0, 0, 0);
          c3 = __builtin_amdgcn_mfma_f32_16x16x32_f16(a, bcf(wlA[(1 * 8 + ks) * 256 + m * 64 + l]), c3, 0, 0, 0);
        }
        pre[4] = c0[0]; pre[5] = c1[0]; pre[6] = c2[0]; pre[7] = c3[0];
      }
      float i0 = sigm_f(pre[0] + xc[0]);
      float i1 = sigm_f(pre[1] + xc[1]);
      float f0 = sigm_f(pre[2] + xc[2]);
      float f1 = sigm_f(pre[3] + xc[3]);
      float g0 = tanh_f(pre[4] + xc[4]);
      float g1 = tanh_f(pre[5] + xc[5]);
      float o0 = sigm_f(pre[6] + xc[6]);
      float o1 = sigm_f(pre[7] + xc[7]);
      cc0 = f0 * cc0 + i0 * g0;
      cc1 = f1 * cc1 + i1 * g1;
      float hv0 = o0 * tanh_f(cc0);
      float hv1 = o1 * tanh_f(cc1);
      if (l < 16) {
        obuf[(size_t)t * 512 + (d << 8) + u0] = hv0;   // fire-and-forget
        obuf[(size_t)t * 512 + (d << 8) + u1] = hv1;
        ushort* hp = (ushort*)hl[p ^ 1];
        hp[u0] = (ushort)(pk(hv0, hv0) & 0xFFFFu);
        hp[u1] = (ushort)(pk(hv1, hv1) & 0xFFFFu);
      }
    } else {
      // ================= fdot2 path (units 128..255) =================
      if (step + 1 < SQ) {
#pragma unroll
        for (int g = 0; g < 4; ++g) xn[g] = xpd[(size_t)(t + dt) * NG + g * 256 + uv];
      }
      const uint4* hb = (const uint4*)&hl[p][s * 64];
      float acc[4] = {0.0f, 0.0f, 0.0f, 0.0f};
#pragma unroll
      for (int q = 0; q < 12; ++q) {
        uint4 hq = hb[q];
        h2 hx = bch2(hq.x), hy = bch2(hq.y), hz = bch2(hq.z), hw = bch2(hq.w);
#pragma unroll
        for (int g = 0; g < 4; ++g) {
          acc[g] = __builtin_amdgcn_fdot2(bch2(wregd[g * 48 + 4 * q + 0]), hx, acc[g], false);
          acc[g] = __builtin_amdgcn_fdot2(bch2(wregd[g * 48 + 4 * q + 1]), hy, acc[g], false);
          acc[g] = __builtin_amdgcn_fdot2(bch2(wregd[g * 48 + 4 * q + 2]), hz, acc[g], false);
          acc[g] = __builtin_amdgcn_fdot2(bch2(wregd[g * 48 + 4 * q + 3]), hw, acc[g], false);
        }
      }
#pragma unroll
      for (int qq = 0; qq < 4; ++qq) {
        uint4 hq = hb[12 + qq];
        h2 hx = bch2(hq.x), hy = bch2(hq.y), hz = bch2(hq.z), hw = bch2(hq.w);
#pragma unroll
        for (int g = 0; g < 4; ++g) {
          uint4 wq = wlV[(g * 4 + qq) * 256 + jv];
          acc[g] = __builtin_amdgcn_fdot2(bch2(wq.x), hx, acc[g], false);
          acc[g] = __builtin_amdgcn_fdot2(bch2(wq.y), hy, acc[g], false);
          acc[g] = __builtin_amdgcn_fdot2(bch2(wq.z), hz, acc[g], false);
          acc[g] = __builtin_amdgcn_fdot2(bch2(wq.w), hw, acc[g], false);
        }
      }
#pragma unroll
      for (int g = 0; g < 4; ++g) acc[g] += dpp_xor1(acc[g]);
      float iv = sigm_f(acc[0] + xc[0]);
      float fv = sigm_f(acc[1] + xc[1]);
      float gv = tanh_f(acc[2] + xc[2]);
      float ov = sigm_f(acc[3] + xc[3]);
      cc = fv * cc + iv * gv;
      float hv = ov * tanh_f(cc);
      if (s == 0) {
        obuf[(size_t)t * 512 + (d << 8) + uv] = hv;    // fire-and-forget
        ((ushort*)hl[p ^ 1])[uv] = (ushort)(pk(hv, hv) & 0xFFFFu);
      }
    }

    // ---- one raw barrier: LDS ordering only, no vmcnt drain ----
    asm volatile("s_waitcnt lgkmcnt(0)" ::: "memory");
    __builtin_amdgcn_s_barrier();
    __builtin_amdgcn_sched_barrier(0);

    p ^= 1;
#pragma unroll
    for (int i = 0; i < 8; ++i) xc[i] = xn[i];
    t += dt;
  }
}

// =====================================================================
// classifier head
// =====================================================================
__global__ void cls_k(const float* __restrict__ buf, const float* __restrict__ w1,
                      const float* __restrict__ b1, const float* __restrict__ w2,
                      const float* __restrict__ b2, float* __restrict__ out) {
  __shared__ float feat[512];
  __shared__ float hid[32];
  const int t = threadIdx.x;
  feat[t] = (t < 256) ? buf[(size_t)(SQ - 1) * 512 + t] : buf[t];
  __syncthreads();
  if (t < 32) {
    float a = b1[t];
    for (int k = 0; k < 512; ++k) a = fmaf(feat[k], w1[k * 32 + t], a);
    hid[t] = a;
  }
  __syncthreads();
  if (t < 2) {
    float a = b2[t];
    for (int k = 0; k < 32; ++k) a = fmaf(hid[k], w2[k * 2 + t], a);
    out[t] = a;
  }
}

// =====================================================================
extern "C" void kernel_launch(void* const* d_in, const int* in_sizes, int n_in,
                              void* d_out, int out_size, void* d_ws, size_t ws_size,
                              hipStream_t stream) {
  const float* x     = (const float*)d_in[0];
  const float* w_ih0 = (const float*)d_in[1];
  const float* w_hh0 = (const float*)d_in[2];
  const float* b0    = (const float*)d_in[3];
  const float* w_ih  = (const float*)d_in[4];
  const float* w_hh  = (const float*)d_in[5];
  const float* b     = (const float*)d_in[6];
  const float* w1    = (const float*)d_in[7];
  const float* b1    = (const float*)d_in[8];
  const float* w2    = (const float*)d_in[9];
  const float* b2    = (const float*)d_in[10];

  float* xp   = (float*)d_ws;                       // [2][SQ][NG] = 64MB
  float* bufA = xp + (size_t)2 * SQ * NG;           // [SQ][512]   = 16MB
  float* bufB = bufA + (size_t)SQ * 512;            // [SQ][512]   = 16MB

  const dim3 ggrid(SQ / 64, 32);

  // layer 0
  gemm_mfma<<<ggrid, 256, 0, stream>>>(x, 1024, w_ih0, b0, xp);
  lstm_hyb<<<2, 512, 0, stream>>>(w_hh0, xp, bufA);

  // layers 1..4
  float* cur = bufA;
  float* nxt = bufB;
  for (int lyr = 0; lyr < 4; ++lyr) {
    gemm_mfma<<<ggrid, 256, 0, stream>>>(cur, 512, w_ih + (size_t)lyr * 2 * 512 * 1024,
                                         b + (size_t)lyr * 2 * 1024, xp);
    lstm_hyb<<<2, 512, 0, stream>>>(w_hh + (size_t)lyr * 2 * 256 * 1024, xp, nxt);
    float* tmp = cur; cur = nxt; nxt = tmp;
  }

  cls_k<<<1, 512, 0, stream>>>(cur, w1, b1, w2, b2, (float*)d_out);
}